// Round 5
// baseline (837.682 us; speedup 1.0000x reference)
//
#include <hip/hip_runtime.h>
#include <hip/hip_bf16.h>
#include <math.h>

// Problem dims (fixed by reference): T=2, B=16, L=2048, D=512, G=1024
#define TT 2
#define BB 16
#define LL 2048
#define NN 4096   // T*L
#define DD 512
#define GG 1024
#define SCALE 0.044194173824159216f   // 1/sqrt(512)
#define LOG2E 1.4426950408889634f
#define QSCL (SCALE * LOG2E)          // fold into q so scores are in log2 units
#define C_IP 0.051905126482615036f    // log2(10000)/256

typedef unsigned short ushort_t;
typedef short short8 __attribute__((ext_vector_type(8)));   // 8 bf16 = 4 VGPR (MFMA A/B frag)
typedef float f32x4 __attribute__((ext_vector_type(4)));    // MFMA C/D frag

__device__ __forceinline__ float inv_pos_f(int dhalf) {
    return exp2f(-C_IP * (float)dhalf);
}
__device__ __forceinline__ unsigned short f2b(float f) {  // fp32 -> bf16 bits, RNE
    union { float f; unsigned u; } x; x.f = f;
    unsigned r = x.u + 0x7fffu + ((x.u >> 16) & 1u);
    return (unsigned short)(r >> 16);
}
__device__ __forceinline__ float b2f(unsigned short u) {
    union { unsigned u; float f; } x; x.u = ((unsigned)u) << 16;
    return x.f;
}

// ---------------- fused emb + embT generator ----------------
__global__ void gen_kernel(const float* __restrict__ times,
                           const float* __restrict__ type_emb,
                           ushort_t* __restrict__ emb,
                           ushort_t* __restrict__ embT) {
    __shared__ float s_tm[64];
    __shared__ float s_te[DD];
    const int bid = blockIdx.x;
    const int b = bid >> 6;
    const int ntile = bid & 63;            // 64-n tile; t = ntile>>5
    const int t = ntile >> 5;
    const int l0 = (ntile & 31) * 64;
    const int tid = threadIdx.x;           // 256

    if (tid < 64) s_tm[tid] = times[(size_t)(t * BB + b) * LL + l0 + tid];
    s_te[tid]       = type_emb[t * DD + tid];
    s_te[tid + 256] = type_emb[t * DD + tid + 256];
    __syncthreads();

    // ---- phase A: emb[b][n][d] rows
    {
        const int rsub = tid >> 3;
        const int coff = (tid & 7) * 8;
#pragma unroll
        for (int i = 0; i < 2; ++i) {
            const int rr = i * 32 + rsub;
            const float tm = s_tm[rr];
            const float pad = (tm != 0.0f) ? 1.0f : 0.0f;
            ushort_t* dst = emb + ((size_t)b * NN + (size_t)ntile * 64 + rr) * DD;
#pragma unroll
            for (int k = 0; k < 8; ++k) {
                const int d0 = k * 64 + coff;
                union { ushort_t us[8]; short8 v; } o;
#pragma unroll
                for (int j = 0; j < 4; ++j) {
                    const float th = tm * inv_pos_f((d0 >> 1) + j);
                    o.us[2 * j]     = f2b((__sinf(th) + s_te[d0 + 2 * j]) * pad);
                    o.us[2 * j + 1] = f2b((__cosf(th) + s_te[d0 + 2 * j + 1]) * pad);
                }
                *reinterpret_cast<short8*>(dst + d0) = o.v;
            }
        }
    }

    // ---- phase B: embT[b][d][n] rows (recompute, coalesced both ways)
    {
        const int dsub = tid >> 3;
        const int nc = (tid & 7) * 8;
#pragma unroll 4
        for (int pass = 0; pass < 16; ++pass) {
            const int d = pass * 32 + dsub;
            const float ip = inv_pos_f(d >> 1);
            const float te = s_te[d];
            const bool use_cos = (d & 1);
            union { ushort_t us[8]; short8 v; } o;
#pragma unroll
            for (int j = 0; j < 8; ++j) {
                const float tm = s_tm[nc + j];
                const float th = tm * ip;
                const float v = use_cos ? __cosf(th) : __sinf(th);
                o.us[j] = f2b((v + te) * ((tm != 0.0f) ? 1.0f : 0.0f));
            }
            *reinterpret_cast<short8*>(
                embT + ((size_t)b * DD + d) * NN + (size_t)ntile * 64 + nc) = o.v;
        }
    }
}

// ---------------- q table (bf16, pre-scaled): q'[g][d] ----------------
__global__ void qb_kernel(ushort_t* __restrict__ qb) {
    const int g = blockIdx.x;
    const int tid = threadIdx.x;  // 128
    const float mid = (float)g + 0.5f;
#pragma unroll
    for (int i = 0; i < 4; ++i) {
        int d = i * 128 + tid;
        float theta = mid * inv_pos_f(d >> 1);
        float v = (d & 1) ? cosf(theta) : sinf(theta);
        qb[(size_t)g * DD + d] = f2b(v * QSCL);
    }
}

// ---------------- flash attention, NS-way n-split, bf16 partials ----------------
// Fixed-shift softmax: P = exp2(s' - 4); partials are pure sums -> combine adds.
// NS splits of TPS=128/NS tiles (aligned to the t-boundary at tile 64, NS>=2).
// Grid NS*512 > residency (4 blocks/CU) -> HW queue rebalances ragged rl.
template <int NS>
__global__ __launch_bounds__(256, 4)
void attn3(const ushort_t* __restrict__ emb,
           const ushort_t* __restrict__ embT,
           const ushort_t* __restrict__ qb,
           const int* __restrict__ real_len,
           ushort_t* __restrict__ pO,         // [NS][B][G][D] bf16 partial O
           float* __restrict__ pl) {          // [NS][B][G] partial l
    __shared__ __align__(16) ushort_t sA[32 * 520];  // emb tile, row stride 1040B
    __shared__ __align__(16) ushort_t sP[32 * 40];   // P [g][n], row stride 80B
    __shared__ float s_lred[2][32];

    constexpr int TPS = 128 / NS;             // tiles per split
    const int idx = blockIdx.x;               // low 3 bits = XCD slot = b%8
    const int xcd = idx & 7;
    const int gt = (idx >> 3) & 31;
    const int hi = idx >> 8;                  // [0, NS*2)
    const int b = xcd + ((hi & 1) << 3);
    const int s = hi >> 1;
    const int g0 = gt * 32;

    const int tid = threadIdx.x;              // 256
    const int lane = tid & 63;
    const int w = tid >> 6;                   // 4 waves
    const int l15 = lane & 15;
    const int quad = lane >> 4;               // 0..3
    const int mt1 = w >> 1;                   // GEMM1 n-tile (0/1)
    const int gt1 = w & 1;                    // GEMM1 g-tile (0/1)

    // q B-fragments resident: lane holds q'[g0+gt1*16+l15][kc*32+quad*8+j]
    short8 qf[16];
    {
        const ushort_t* qrow = qb + (size_t)(g0 + gt1 * 16 + l15) * DD + quad * 8;
#pragma unroll
        for (int kc = 0; kc < 16; ++kc)
            qf[kc] = *reinterpret_cast<const short8*>(qrow + kc * 32);
    }

    const ushort_t* embB  = emb  + (size_t)b * NN * DD;
    const ushort_t* embTB = embT + (size_t)b * DD * NN;

    const int rl0 = real_len[b];
    const int rl1 = real_len[BB + b];
    const int e0 = (rl0 + 31) >> 5;           // valid tiles in t0 half [0,64)
    const int e1 = (rl1 + 31) >> 5;           // valid tiles in t1 half [64,128)
    const int first = s * TPS;                // split never crosses tile 64
    int count;
    if (first < 64) count = min(max(e0 - first, 0), TPS);
    else            count = min(max(64 + e1 - first, 0), TPS);

    f32x4 accO[8][2];
#pragma unroll
    for (int i = 0; i < 8; ++i) { accO[i][0] = (f32x4)0.f; accO[i][1] = (f32x4)0.f; }
    float ls = 0.f;

    auto stage = [&](int nt) {
        const ushort_t* src = embB + (size_t)(nt * 32 + w * 8) * DD + lane * 8;
        ushort_t* dst = sA + (w * 8) * 520;
#pragma unroll
        for (int i = 0; i < 8; ++i) {
            __builtin_amdgcn_global_load_lds(
                (const __attribute__((address_space(1))) unsigned int*)(src + (size_t)i * DD),
                (__attribute__((address_space(3))) unsigned int*)(dst + i * 520),
                16, 0, 0);
        }
    };
    short8 tf[8];
    auto prefetchT = [&](int nt) {
        const ushort_t* trow = embTB + (size_t)(w * 128 + l15) * NN + nt * 32 + quad * 8;
#pragma unroll
        for (int mt = 0; mt < 8; ++mt)
            tf[mt] = *reinterpret_cast<const short8*>(trow + (size_t)mt * 16 * NN);
    };

    if (count > 0) { stage(first); prefetchT(first); }

    for (int k = 0; k < count; ++k) {
        const int cur = first + k;
        __syncthreads();   // B1: sA staged + tf loaded (vmcnt drain), sP consumed

        // ---- GEMM1: two independent 8-MFMA chains
        f32x4 S0 = (f32x4)0.f, S1 = (f32x4)0.f;
        {
            const ushort_t* arow = sA + (mt1 * 16 + l15) * 520 + quad * 8;
#pragma unroll
            for (int kc = 0; kc < 8; ++kc) {
                short8 a0 = *reinterpret_cast<const short8*>(arow + (2 * kc) * 32);
                short8 a1 = *reinterpret_cast<const short8*>(arow + (2 * kc + 1) * 32);
                S0 = __builtin_amdgcn_mfma_f32_16x16x32_bf16(a0, qf[2 * kc],     S0, 0, 0, 0);
                S1 = __builtin_amdgcn_mfma_f32_16x16x32_bf16(a1, qf[2 * kc + 1], S1, 0, 0, 0);
            }
        }

        // ---- mask + fixed-shift exp2; accumulate l in regs; pack P to LDS
        const int n0 = cur * 32;
        const int nb = n0 + mt1 * 16 + quad * 4;
        const int rl = (nb >= LL) ? rl1 : rl0;
        const int lb = nb & (LL - 1);
        float p[4];
#pragma unroll
        for (int r = 0; r < 4; ++r)
            p[r] = (lb + r < rl) ? exp2f(S0[r] + S1[r] - 4.0f) : 0.0f;
        ls += (p[0] + p[1]) + (p[2] + p[3]);
        {
            union { unsigned short us[4]; unsigned long long u64; } pk;
            pk.us[0] = f2b(p[0]); pk.us[1] = f2b(p[1]); pk.us[2] = f2b(p[2]); pk.us[3] = f2b(p[3]);
            *reinterpret_cast<unsigned long long*>(
                sP + (gt1 * 16 + l15) * 40 + mt1 * 16 + quad * 4) = pk.u64;
        }
        __syncthreads();   // B2: sP ready, sA reads done

        if (k + 1 < count) stage(cur + 1);    // DMA overlaps GEMM2 + next GEMM1

        // ---- GEMM2: A = tf regs (prefetched), B = P from LDS
        {
            short8 bP0 = *reinterpret_cast<const short8*>(sP + l15 * 40 + quad * 8);
            short8 bP1 = *reinterpret_cast<const short8*>(sP + (16 + l15) * 40 + quad * 8);
#pragma unroll
            for (int mt = 0; mt < 8; ++mt) {
                accO[mt][0] = __builtin_amdgcn_mfma_f32_16x16x32_bf16(tf[mt], bP0, accO[mt][0], 0, 0, 0);
                accO[mt][1] = __builtin_amdgcn_mfma_f32_16x16x32_bf16(tf[mt], bP1, accO[mt][1], 0, 0, 0);
            }
        }
        if (k + 1 < count) prefetchT(cur + 1);
    }

    // ---- l reduction: quads via shfl, mt1 halves via LDS
    ls += __shfl_xor(ls, 16, 64);
    ls += __shfl_xor(ls, 32, 64);
    if (lane < 16) s_lred[mt1][gt1 * 16 + lane] = ls;
    __syncthreads();

    if (w == 0 && lane < 32)
        pl[((size_t)s * BB + b) * GG + g0 + lane] = s_lred[0][lane] + s_lred[1][lane];

    ushort_t* po = pO + (((size_t)s * BB + b) * GG) * DD;
#pragma unroll
    for (int mt = 0; mt < 8; ++mt) {
#pragma unroll
        for (int gtt = 0; gtt < 2; ++gtt) {
            union { unsigned short us[4]; unsigned long long u64; } pk;
            pk.us[0] = f2b(accO[mt][gtt][0]); pk.us[1] = f2b(accO[mt][gtt][1]);
            pk.us[2] = f2b(accO[mt][gtt][2]); pk.us[3] = f2b(accO[mt][gtt][3]);
            const int g = g0 + gtt * 16 + l15;
            const int d = w * 128 + mt * 16 + quad * 4;
            *reinterpret_cast<unsigned long long*>(po + (size_t)g * DD + d) = pk.u64;
        }
    }
}

// ---------------- combine: out = (Σ_s O_s) / (Σ_s l_s) ----------------
template <int NS>
__global__ void combine3(const ushort_t* __restrict__ pO,
                         const float* __restrict__ pl,
                         float* __restrict__ out) {
    const size_t i4 = (size_t)blockIdx.x * 256 + threadIdx.x;
    const size_t base = i4 * 4;                 // 4 d's
    const size_t bg = base >> 9;                // (b*G+g), DD=512
    float lsum = 0.f;
#pragma unroll
    for (int s = 0; s < NS; ++s) lsum += pl[(size_t)s * BB * GG + bg];
    const float inv = 1.0f / lsum;
    float o[4] = {0.f, 0.f, 0.f, 0.f};
#pragma unroll
    for (int s = 0; s < NS; ++s) {
        union { unsigned long long u64; unsigned short us[4]; } pk;
        pk.u64 = *reinterpret_cast<const unsigned long long*>(
            pO + (size_t)s * BB * GG * DD + base);
#pragma unroll
        for (int j = 0; j < 4; ++j) o[j] += b2f(pk.us[j]);
    }
    float4 v;
    v.x = o[0] * inv; v.y = o[1] * inv; v.z = o[2] * inv; v.w = o[3] * inv;
    *reinterpret_cast<float4*>(out + base) = v;
}

// ---------------- non-split flash (mid-ws fallback, proven R3/R4 path) ----------------
__global__ __launch_bounds__(256, 2)
void attn2ns(const ushort_t* __restrict__ emb,
             const ushort_t* __restrict__ embT,
             const ushort_t* __restrict__ qb,
             const int* __restrict__ real_len,
             float* __restrict__ outp) {
    __shared__ __align__(16) ushort_t sA[32 * 520];
    __shared__ __align__(16) ushort_t sP[32 * 40];
    __shared__ float s_lred[2][32];

    const int idx = blockIdx.x;
    const int xcd = idx & 7;
    const int gt = (idx >> 3) & 31;
    const int b = xcd + ((idx >> 8) << 3);
    const int g0 = gt * 32;

    const int tid = threadIdx.x;
    const int lane = tid & 63;
    const int w = tid >> 6;
    const int l15 = lane & 15;
    const int quad = lane >> 4;
    const int mt1 = w >> 1;
    const int gt1 = w & 1;

    short8 qf[16];
    {
        const ushort_t* qrow = qb + (size_t)(g0 + gt1 * 16 + l15) * DD + quad * 8;
#pragma unroll
        for (int kc = 0; kc < 16; ++kc)
            qf[kc] = *reinterpret_cast<const short8*>(qrow + kc * 32);
    }

    const ushort_t* embB  = emb  + (size_t)b * NN * DD;
    const ushort_t* embTB = embT + (size_t)b * DD * NN;

    const int rl0 = real_len[b];
    const int rl1 = real_len[BB + b];
    const int e0 = (rl0 + 31) >> 5;
    const int count = e0 + ((rl1 + 31) >> 5);

    f32x4 accO[8][2];
#pragma unroll
    for (int i = 0; i < 8; ++i) { accO[i][0] = (f32x4)0.f; accO[i][1] = (f32x4)0.f; }
    float ls = 0.f;

    auto stage = [&](int nt) {
        const ushort_t* src = embB + (size_t)(nt * 32 + w * 8) * DD + lane * 8;
        ushort_t* dst = sA + (w * 8) * 520;
#pragma unroll
        for (int i = 0; i < 8; ++i) {
            __builtin_amdgcn_global_load_lds(
                (const __attribute__((address_space(1))) unsigned int*)(src + (size_t)i * DD),
                (__attribute__((address_space(3))) unsigned int*)(dst + i * 520),
                16, 0, 0);
        }
    };
    short8 tf[8];
    auto prefetchT = [&](int nt) {
        const ushort_t* trow = embTB + (size_t)(w * 128 + l15) * NN + nt * 32 + quad * 8;
#pragma unroll
        for (int mt = 0; mt < 8; ++mt)
            tf[mt] = *reinterpret_cast<const short8*>(trow + (size_t)mt * 16 * NN);
    };

    int cur = 0;
    stage(0); prefetchT(0);

    for (int k = 0; k < count; ++k) {
        const int nxt = (cur + 1 == e0) ? 64 : cur + 1;
        __syncthreads();
        f32x4 S0 = (f32x4)0.f, S1 = (f32x4)0.f;
        {
            const ushort_t* arow = sA + (mt1 * 16 + l15) * 520 + quad * 8;
#pragma unroll
            for (int kc = 0; kc < 8; ++kc) {
                short8 a0 = *reinterpret_cast<const short8*>(arow + (2 * kc) * 32);
                short8 a1 = *reinterpret_cast<const short8*>(arow + (2 * kc + 1) * 32);
                S0 = __builtin_amdgcn_mfma_f32_16x16x32_bf16(a0, qf[2 * kc],     S0, 0, 0, 0);
                S1 = __builtin_amdgcn_mfma_f32_16x16x32_bf16(a1, qf[2 * kc + 1], S1, 0, 0, 0);
            }
        }
        const int n0 = cur * 32;
        const int nb = n0 + mt1 * 16 + quad * 4;
        const int rl = (nb >= LL) ? rl1 : rl0;
        const int lb = nb & (LL - 1);
        float p[4];
#pragma unroll
        for (int r = 0; r < 4; ++r)
            p[r] = (lb + r < rl) ? exp2f(S0[r] + S1[r] - 4.0f) : 0.0f;
        ls += (p[0] + p[1]) + (p[2] + p[3]);
        {
            union { unsigned short us[4]; unsigned long long u64; } pk;
            pk.us[0] = f2b(p[0]); pk.us[1] = f2b(p[1]); pk.us[2] = f2b(p[2]); pk.us[3] = f2b(p[3]);
            *reinterpret_cast<unsigned long long*>(
                sP + (gt1 * 16 + l15) * 40 + mt1 * 16 + quad * 4) = pk.u64;
        }
        __syncthreads();
        if (k + 1 < count) stage(nxt);
        {
            short8 bP0 = *reinterpret_cast<const short8*>(sP + l15 * 40 + quad * 8);
            short8 bP1 = *reinterpret_cast<const short8*>(sP + (16 + l15) * 40 + quad * 8);
#pragma unroll
            for (int mt = 0; mt < 8; ++mt) {
                accO[mt][0] = __builtin_amdgcn_mfma_f32_16x16x32_bf16(tf[mt], bP0, accO[mt][0], 0, 0, 0);
                accO[mt][1] = __builtin_amdgcn_mfma_f32_16x16x32_bf16(tf[mt], bP1, accO[mt][1], 0, 0, 0);
            }
        }
        if (k + 1 < count) prefetchT(nxt);
        cur = nxt;
    }

    ls += __shfl_xor(ls, 16, 64);
    ls += __shfl_xor(ls, 32, 64);
    if (lane < 16) s_lred[mt1][gt1 * 16 + lane] = ls;
    __syncthreads();

    const float il0 = 1.f / (s_lred[0][l15] + s_lred[1][l15]);
    const float il1 = 1.f / (s_lred[0][16 + l15] + s_lred[1][16 + l15]);
#pragma unroll
    for (int mt = 0; mt < 8; ++mt) {
#pragma unroll
        for (int gtt = 0; gtt < 2; ++gtt) {
            const float il = gtt ? il1 : il0;
            float4 v;
            v.x = accO[mt][gtt][0] * il; v.y = accO[mt][gtt][1] * il;
            v.z = accO[mt][gtt][2] * il; v.w = accO[mt][gtt][3] * il;
            const int g = g0 + gtt * 16 + l15;
            const int d = w * 128 + mt * 16 + quad * 4;
            *reinterpret_cast<float4*>(outp + ((size_t)b * GG + g) * DD + d) = v;
        }
    }
}

// ---------------- round-2 proven fallback (tiny ws) ----------------
__global__ void emb_kernel(const float* __restrict__ times,
                           const float* __restrict__ type_emb,
                           ushort_t* __restrict__ emb) {
    const int row = blockIdx.x;
    const int b = row >> 12;
    const int n = row & (NN - 1);
    const int t = n >> 11;
    const int l = n & (LL - 1);
    const float tm = times[(size_t)(t * BB + b) * LL + l];
    const float pad = (tm != 0.0f) ? 1.0f : 0.0f;
    const int tid = threadIdx.x;
#pragma unroll
    for (int i = 0; i < 2; ++i) {
        int d = i * 256 + tid;
        float theta = tm * inv_pos_f(d >> 1);
        float v = (d & 1) ? cosf(theta) : sinf(theta);
        v = (v + type_emb[t * DD + d]) * pad;
        emb[(size_t)row * DD + d] = f2b(v);
    }
}
__global__ void qgrid_kernel(float* __restrict__ qbuf) {
    const int g = blockIdx.x;
    const int tid = threadIdx.x;
    const float mid = (float)g + 0.5f;
#pragma unroll
    for (int i = 0; i < 4; ++i) {
        int d = i * 128 + tid;
        float theta = mid * inv_pos_f(d >> 1);
        float v = (d & 1) ? cosf(theta) : sinf(theta);
        qbuf[(size_t)g * DD + d] = v;
    }
}
__global__ void attn_kernel(const ushort_t* __restrict__ emb,
                            const float* __restrict__ qbuf,
                            const int* __restrict__ real_len,
                            float* __restrict__ out) {
    __shared__ float s_lds[NN];
    __shared__ float q_s[DD];
    __shared__ float red[8];
    const int blk = blockIdx.x;
    const int b = blk >> 10;
    const int g = blk & (GG - 1);
    const int tid = threadIdx.x;
    const int lane = tid & 63;
    const int wave = tid >> 6;
    q_s[tid]       = qbuf[(size_t)g * DD + tid];
    q_s[tid + 256] = qbuf[(size_t)g * DD + tid + 256];
    __syncthreads();
    float qr[8];
#pragma unroll
    for (int j = 0; j < 8; ++j) qr[j] = q_s[lane * 8 + j];
    const unsigned int* embB =
        reinterpret_cast<const unsigned int*>(emb) + (size_t)b * NN * (DD / 2);
#pragma unroll 2
    for (int it = 0; it < NN / 4; ++it) {
        const int n = it * 4 + wave;
        const uint4 raw = *reinterpret_cast<const uint4*>(embB + (size_t)n * (DD / 2) + lane * 4);
        float sacc = 0.f;
        sacc = fmaf(__uint_as_float(raw.x << 16),         qr[0], sacc);
        sacc = fmaf(__uint_as_float(raw.x & 0xffff0000u), qr[1], sacc);
        sacc = fmaf(__uint_as_float(raw.y << 16),         qr[2], sacc);
        sacc = fmaf(__uint_as_float(raw.y & 0xffff0000u), qr[3], sacc);
        sacc = fmaf(__uint_as_float(raw.z << 16),         qr[4], sacc);
        sacc = fmaf(__uint_as_float(raw.z & 0xffff0000u), qr[5], sacc);
        sacc = fmaf(__uint_as_float(raw.w << 16),         qr[6], sacc);
        sacc = fmaf(__uint_as_float(raw.w & 0xffff0000u), qr[7], sacc);
#pragma unroll
        for (int off = 32; off; off >>= 1) sacc += __shfl_xor(sacc, off, 64);
        if (lane == 0) s_lds[n] = sacc * SCALE;
    }
    __syncthreads();
    const int rl0 = real_len[b];
    const int rl1 = real_len[BB + b];
    float m = -INFINITY;
    float sv[16];
#pragma unroll
    for (int i = 0; i < 16; ++i) {
        const int n = i * 256 + tid;
        float sc = s_lds[n];
        const int l = n & (LL - 1);
        const bool valid = l < ((n < LL) ? rl0 : rl1);
        sc = valid ? sc : -INFINITY;
        sv[i] = sc;
        m = fmaxf(m, sc);
    }
#pragma unroll
    for (int off = 32; off; off >>= 1) m = fmaxf(m, __shfl_xor(m, off, 64));
    if (lane == 0) red[wave] = m;
    __syncthreads();
    m = fmaxf(fmaxf(red[0], red[1]), fmaxf(red[2], red[3]));
    float lsum = 0.f;
#pragma unroll
    for (int i = 0; i < 16; ++i) {
        const int n = i * 256 + tid;
        const float e = expf(sv[i] - m);
        s_lds[n] = e;
        lsum += e;
    }
#pragma unroll
    for (int off = 32; off; off >>= 1) lsum += __shfl_xor(lsum, off, 64);
    if (lane == 0) red[4 + wave] = lsum;
    __syncthreads();
    const float inv_l = 1.0f / (red[4] + red[5] + red[6] + red[7]);
    float acc[8] = {0.f, 0.f, 0.f, 0.f, 0.f, 0.f, 0.f, 0.f};
#pragma unroll 2
    for (int kk = 0; kk < NN / 4; ++kk) {
        const int n = kk * 4 + wave;
        const float p = s_lds[n];
        const uint4 raw = *reinterpret_cast<const uint4*>(embB + (size_t)n * (DD / 2) + lane * 4);
        acc[0] = fmaf(p, __uint_as_float(raw.x << 16),         acc[0]);
        acc[1] = fmaf(p, __uint_as_float(raw.x & 0xffff0000u), acc[1]);
        acc[2] = fmaf(p, __uint_as_float(raw.y << 16),         acc[2]);
        acc[3] = fmaf(p, __uint_as_float(raw.y & 0xffff0000u), acc[3]);
        acc[4] = fmaf(p, __uint_as_float(raw.z << 16),         acc[4]);
        acc[5] = fmaf(p, __uint_as_float(raw.z & 0xffff0000u), acc[5]);
        acc[6] = fmaf(p, __uint_as_float(raw.w << 16),         acc[6]);
        acc[7] = fmaf(p, __uint_as_float(raw.w & 0xffff0000u), acc[7]);
    }
    __syncthreads();
    *reinterpret_cast<float4*>(&s_lds[wave * DD + lane * 8])     = make_float4(acc[0], acc[1], acc[2], acc[3]);
    *reinterpret_cast<float4*>(&s_lds[wave * DD + lane * 8 + 4]) = make_float4(acc[4], acc[5], acc[6], acc[7]);
    __syncthreads();
    {
        const int d0 = tid * 2;
        const float o0 = (s_lds[d0]     + s_lds[DD + d0]     + s_lds[2 * DD + d0]     + s_lds[3 * DD + d0])     * inv_l;
        const float o1 = (s_lds[d0 + 1] + s_lds[DD + d0 + 1] + s_lds[2 * DD + d0 + 1] + s_lds[3 * DD + d0 + 1]) * inv_l;
        *reinterpret_cast<float2*>(out + (size_t)blk * DD + d0) = make_float2(o0, o1);
    }
}

extern "C" void kernel_launch(void* const* d_in, const int* in_sizes, int n_in,
                              void* d_out, int out_size, void* d_ws, size_t ws_size,
                              hipStream_t stream) {
    const float* times    = (const float*)d_in[0];
    const float* type_emb = (const float*)d_in[1];
    const int*   real_len = (const int*)d_in[2];
    float* out = (float*)d_out;

    const size_t embBytes = (size_t)BB * NN * DD * sizeof(ushort_t);     // 64 MiB
    const size_t qbBytes  = (size_t)GG * DD * sizeof(ushort_t);          // 1 MiB
    const size_t pOslice  = (size_t)BB * GG * DD * sizeof(ushort_t);     // 16 MiB (bf16)
    const size_t plslice  = (size_t)BB * GG * sizeof(float);             // 64 KiB
    const size_t needFast = 2 * embBytes + qbBytes;                      // 129 MiB
    const size_t need4 = needFast + 4 * (pOslice + plslice);             // ~193.3 MiB
    const size_t need2 = needFast + 2 * (pOslice + plslice);             // ~161.1 MiB

    ushort_t* emb = (ushort_t*)d_ws;

    if (ws_size >= needFast) {
        ushort_t* embT = (ushort_t*)((char*)d_ws + embBytes);
        ushort_t* qb   = (ushort_t*)((char*)d_ws + 2 * embBytes);
        gen_kernel<<<BB * 64, 256, 0, stream>>>(times, type_emb, emb, embT);
        qb_kernel<<<GG, 128, 0, stream>>>(qb);
        if (ws_size >= need4) {
            ushort_t* pO = (ushort_t*)((char*)d_ws + needFast);
            float* pl = (float*)((char*)d_ws + needFast + 4 * pOslice);
            attn3<4><<<4 * 512, 256, 0, stream>>>(emb, embT, qb, real_len, pO, pl);
            combine3<4><<<(BB * GG * DD) / (256 * 4), 256, 0, stream>>>(pO, pl, out);
        } else if (ws_size >= need2) {
            ushort_t* pO = (ushort_t*)((char*)d_ws + needFast);
            float* pl = (float*)((char*)d_ws + needFast + 2 * pOslice);
            attn3<2><<<2 * 512, 256, 0, stream>>>(emb, embT, qb, real_len, pO, pl);
            combine3<2><<<(BB * GG * DD) / (256 * 4), 256, 0, stream>>>(pO, pl, out);
        } else {
            attn2ns<<<512, 256, 0, stream>>>(emb, embT, qb, real_len, out);
        }
    } else {
        // fallback: 66 MiB footprint (proven in round 2)
        float* qbuf = (float*)((char*)d_ws + embBytes);
        emb_kernel<<<BB * NN, 256, 0, stream>>>(times, type_emb, emb);
        qgrid_kernel<<<GG, 128, 0, stream>>>(qbuf);
        attn_kernel<<<BB * GG, 256, 0, stream>>>(emb, qbuf, real_len, out);
    }
}

// Round 6
// 337.448 us; speedup vs baseline: 2.4824x; 2.4824x over previous
//
#include <hip/hip_runtime.h>
#include <hip/hip_bf16.h>
#include <math.h>

// Problem dims (fixed by reference): T=2, B=16, L=2048, D=512, G=1024
#define TT 2
#define BB 16
#define LL 2048
#define NN 4096   // T*L
#define DD 512
#define GG 1024
#define SCALE 0.044194173824159216f   // 1/sqrt(512)
#define LOG2E 1.4426950408889634f
#define QSCL (SCALE * LOG2E)          // fold into q so scores are in log2 units
#define C_IP 0.051905126482615036f    // log2(10000)/256

typedef unsigned short ushort_t;
typedef short short8 __attribute__((ext_vector_type(8)));   // 8 bf16 = 4 VGPR (MFMA A/B frag)
typedef float f32x4 __attribute__((ext_vector_type(4)));    // MFMA C/D frag

__device__ __forceinline__ float inv_pos_f(int dhalf) {
    return exp2f(-C_IP * (float)dhalf);
}
__device__ __forceinline__ unsigned short f2b(float f) {  // fp32 -> bf16 bits, RNE
    union { float f; unsigned u; } x; x.f = f;
    unsigned r = x.u + 0x7fffu + ((x.u >> 16) & 1u);
    return (unsigned short)(r >> 16);
}
__device__ __forceinline__ float b2f(unsigned short u) {
    union { unsigned u; float f; } x; x.u = ((unsigned)u) << 16;
    return x.f;
}

// ---------------- fused emb + embT generator ----------------
__global__ void gen_kernel(const float* __restrict__ times,
                           const float* __restrict__ type_emb,
                           ushort_t* __restrict__ emb,
                           ushort_t* __restrict__ embT) {
    __shared__ float s_tm[64];
    __shared__ float s_te[DD];
    const int bid = blockIdx.x;
    const int b = bid >> 6;
    const int ntile = bid & 63;            // 64-n tile; t = ntile>>5
    const int t = ntile >> 5;
    const int l0 = (ntile & 31) * 64;
    const int tid = threadIdx.x;           // 256

    if (tid < 64) s_tm[tid] = times[(size_t)(t * BB + b) * LL + l0 + tid];
    s_te[tid]       = type_emb[t * DD + tid];
    s_te[tid + 256] = type_emb[t * DD + tid + 256];
    __syncthreads();

    // ---- phase A: emb[b][n][d] rows
    {
        const int rsub = tid >> 3;
        const int coff = (tid & 7) * 8;
#pragma unroll
        for (int i = 0; i < 2; ++i) {
            const int rr = i * 32 + rsub;
            const float tm = s_tm[rr];
            const float pad = (tm != 0.0f) ? 1.0f : 0.0f;
            ushort_t* dst = emb + ((size_t)b * NN + (size_t)ntile * 64 + rr) * DD;
#pragma unroll
            for (int k = 0; k < 8; ++k) {
                const int d0 = k * 64 + coff;
                union { ushort_t us[8]; short8 v; } o;
#pragma unroll
                for (int j = 0; j < 4; ++j) {
                    const float th = tm * inv_pos_f((d0 >> 1) + j);
                    o.us[2 * j]     = f2b((__sinf(th) + s_te[d0 + 2 * j]) * pad);
                    o.us[2 * j + 1] = f2b((__cosf(th) + s_te[d0 + 2 * j + 1]) * pad);
                }
                *reinterpret_cast<short8*>(dst + d0) = o.v;
            }
        }
    }

    // ---- phase B: embT[b][d][n] rows (recompute, coalesced both ways)
    {
        const int dsub = tid >> 3;
        const int nc = (tid & 7) * 8;
#pragma unroll 4
        for (int pass = 0; pass < 16; ++pass) {
            const int d = pass * 32 + dsub;
            const float ip = inv_pos_f(d >> 1);
            const float te = s_te[d];
            const bool use_cos = (d & 1);
            union { ushort_t us[8]; short8 v; } o;
#pragma unroll
            for (int j = 0; j < 8; ++j) {
                const float tm = s_tm[nc + j];
                const float th = tm * ip;
                const float v = use_cos ? __cosf(th) : __sinf(th);
                o.us[j] = f2b((v + te) * ((tm != 0.0f) ? 1.0f : 0.0f));
            }
            *reinterpret_cast<short8*>(
                embT + ((size_t)b * DD + d) * NN + (size_t)ntile * 64 + nc) = o.v;
        }
    }
}

// ---------------- q table (bf16, pre-scaled): q'[g][d] ----------------
__global__ void qb_kernel(ushort_t* __restrict__ qb) {
    const int g = blockIdx.x;
    const int tid = threadIdx.x;  // 128
    const float mid = (float)g + 0.5f;
#pragma unroll
    for (int i = 0; i < 4; ++i) {
        int d = i * 128 + tid;
        float theta = mid * inv_pos_f(d >> 1);
        float v = (d & 1) ? cosf(theta) : sinf(theta);
        qb[(size_t)g * DD + d] = f2b(v * QSCL);
    }
}

// ---------------- flash attention, NS-way n-split, bf16 partials ----------------
// Fixed-shift softmax: P = exp2(s' - 4); partials are pure sums -> combine adds.
// __launch_bounds__(256,2): R5 taught us (256,4) forces VGPR 104->64 and
// spills qf/tf to scratch (1.3 GB of HBM traffic). Keep the allocator free.
template <int NS>
__global__ __launch_bounds__(256, 2)
void attn3(const ushort_t* __restrict__ emb,
           const ushort_t* __restrict__ embT,
           const ushort_t* __restrict__ qb,
           const int* __restrict__ real_len,
           ushort_t* __restrict__ pO,         // [NS][B][G][D] bf16 partial O
           float* __restrict__ pl) {          // [NS][B][G] partial l
    __shared__ __align__(16) ushort_t sA[32 * 520];  // emb tile, row stride 1040B
    __shared__ __align__(16) ushort_t sP[32 * 40];   // P [g][n], row stride 80B
    __shared__ float s_lred[2][32];

    constexpr int TPS = 128 / NS;             // tiles per split
    const int idx = blockIdx.x;               // low 3 bits = XCD slot = b%8
    const int xcd = idx & 7;
    const int gt = (idx >> 3) & 31;
    const int hi = idx >> 8;                  // [0, NS*2)
    const int b = xcd + ((hi & 1) << 3);
    const int s = hi >> 1;
    const int g0 = gt * 32;

    const int tid = threadIdx.x;              // 256
    const int lane = tid & 63;
    const int w = tid >> 6;                   // 4 waves
    const int l15 = lane & 15;
    const int quad = lane >> 4;               // 0..3
    const int mt1 = w >> 1;                   // GEMM1 n-tile (0/1)
    const int gt1 = w & 1;                    // GEMM1 g-tile (0/1)

    // q B-fragments resident: lane holds q'[g0+gt1*16+l15][kc*32+quad*8+j]
    short8 qf[16];
    {
        const ushort_t* qrow = qb + (size_t)(g0 + gt1 * 16 + l15) * DD + quad * 8;
#pragma unroll
        for (int kc = 0; kc < 16; ++kc)
            qf[kc] = *reinterpret_cast<const short8*>(qrow + kc * 32);
    }

    const ushort_t* embB  = emb  + (size_t)b * NN * DD;
    const ushort_t* embTB = embT + (size_t)b * DD * NN;

    const int rl0 = real_len[b];
    const int rl1 = real_len[BB + b];
    const int e0 = (rl0 + 31) >> 5;           // valid tiles in t0 half [0,64)
    const int e1 = (rl1 + 31) >> 5;           // valid tiles in t1 half [64,128)
    const int first = s * TPS;                // split never crosses tile 64
    int count;
    if (first < 64) count = min(max(e0 - first, 0), TPS);
    else            count = min(max(64 + e1 - first, 0), TPS);

    f32x4 accO[8][2];
#pragma unroll
    for (int i = 0; i < 8; ++i) { accO[i][0] = (f32x4)0.f; accO[i][1] = (f32x4)0.f; }
    float ls = 0.f;

    auto stage = [&](int nt) {
        const ushort_t* src = embB + (size_t)(nt * 32 + w * 8) * DD + lane * 8;
        ushort_t* dst = sA + (w * 8) * 520;
#pragma unroll
        for (int i = 0; i < 8; ++i) {
            __builtin_amdgcn_global_load_lds(
                (const __attribute__((address_space(1))) unsigned int*)(src + (size_t)i * DD),
                (__attribute__((address_space(3))) unsigned int*)(dst + i * 520),
                16, 0, 0);
        }
    };
    short8 tf[8];
    auto prefetchT = [&](int nt) {
        const ushort_t* trow = embTB + (size_t)(w * 128 + l15) * NN + nt * 32 + quad * 8;
#pragma unroll
        for (int mt = 0; mt < 8; ++mt)
            tf[mt] = *reinterpret_cast<const short8*>(trow + (size_t)mt * 16 * NN);
    };

    if (count > 0) { stage(first); prefetchT(first); }

    for (int k = 0; k < count; ++k) {
        const int cur = first + k;
        __syncthreads();   // B1: sA staged + tf loaded (vmcnt drain), sP consumed

        // ---- GEMM1: two independent 8-MFMA chains
        f32x4 S0 = (f32x4)0.f, S1 = (f32x4)0.f;
        {
            const ushort_t* arow = sA + (mt1 * 16 + l15) * 520 + quad * 8;
#pragma unroll
            for (int kc = 0; kc < 8; ++kc) {
                short8 a0 = *reinterpret_cast<const short8*>(arow + (2 * kc) * 32);
                short8 a1 = *reinterpret_cast<const short8*>(arow + (2 * kc + 1) * 32);
                S0 = __builtin_amdgcn_mfma_f32_16x16x32_bf16(a0, qf[2 * kc],     S0, 0, 0, 0);
                S1 = __builtin_amdgcn_mfma_f32_16x16x32_bf16(a1, qf[2 * kc + 1], S1, 0, 0, 0);
            }
        }

        // ---- mask + fixed-shift exp2; accumulate l in regs; pack P to LDS
        const int n0 = cur * 32;
        const int nb = n0 + mt1 * 16 + quad * 4;
        const int rl = (nb >= LL) ? rl1 : rl0;
        const int lb = nb & (LL - 1);
        float p[4];
#pragma unroll
        for (int r = 0; r < 4; ++r)
            p[r] = (lb + r < rl) ? exp2f(S0[r] + S1[r] - 4.0f) : 0.0f;
        ls += (p[0] + p[1]) + (p[2] + p[3]);
        {
            union { unsigned short us[4]; unsigned long long u64; } pk;
            pk.us[0] = f2b(p[0]); pk.us[1] = f2b(p[1]); pk.us[2] = f2b(p[2]); pk.us[3] = f2b(p[3]);
            *reinterpret_cast<unsigned long long*>(
                sP + (gt1 * 16 + l15) * 40 + mt1 * 16 + quad * 4) = pk.u64;
        }
        __syncthreads();   // B2: sP ready, sA reads done

        if (k + 1 < count) stage(cur + 1);    // DMA overlaps GEMM2 + next GEMM1

        // ---- GEMM2: A = tf regs (prefetched), B = P from LDS
        {
            short8 bP0 = *reinterpret_cast<const short8*>(sP + l15 * 40 + quad * 8);
            short8 bP1 = *reinterpret_cast<const short8*>(sP + (16 + l15) * 40 + quad * 8);
#pragma unroll
            for (int mt = 0; mt < 8; ++mt) {
                accO[mt][0] = __builtin_amdgcn_mfma_f32_16x16x32_bf16(tf[mt], bP0, accO[mt][0], 0, 0, 0);
                accO[mt][1] = __builtin_amdgcn_mfma_f32_16x16x32_bf16(tf[mt], bP1, accO[mt][1], 0, 0, 0);
            }
        }
        if (k + 1 < count) prefetchT(cur + 1);
    }

    // ---- l reduction: quads via shfl, mt1 halves via LDS
    ls += __shfl_xor(ls, 16, 64);
    ls += __shfl_xor(ls, 32, 64);
    if (lane < 16) s_lred[mt1][gt1 * 16 + lane] = ls;
    __syncthreads();

    if (w == 0 && lane < 32)
        pl[((size_t)s * BB + b) * GG + g0 + lane] = s_lred[0][lane] + s_lred[1][lane];

    ushort_t* po = pO + (((size_t)s * BB + b) * GG) * DD;
#pragma unroll
    for (int mt = 0; mt < 8; ++mt) {
#pragma unroll
        for (int gtt = 0; gtt < 2; ++gtt) {
            union { unsigned short us[4]; unsigned long long u64; } pk;
            pk.us[0] = f2b(accO[mt][gtt][0]); pk.us[1] = f2b(accO[mt][gtt][1]);
            pk.us[2] = f2b(accO[mt][gtt][2]); pk.us[3] = f2b(accO[mt][gtt][3]);
            const int g = g0 + gtt * 16 + l15;
            const int d = w * 128 + mt * 16 + quad * 4;
            *reinterpret_cast<unsigned long long*>(po + (size_t)g * DD + d) = pk.u64;
        }
    }
}

// ---------------- combine: out = (Σ_s O_s) / (Σ_s l_s) ----------------
template <int NS>
__global__ void combine3(const ushort_t* __restrict__ pO,
                         const float* __restrict__ pl,
                         float* __restrict__ out) {
    const size_t i4 = (size_t)blockIdx.x * 256 + threadIdx.x;
    const size_t base = i4 * 4;                 // 4 d's
    const size_t bg = base >> 9;                // (b*G+g), DD=512
    float lsum = 0.f;
#pragma unroll
    for (int s = 0; s < NS; ++s) lsum += pl[(size_t)s * BB * GG + bg];
    const float inv = 1.0f / lsum;
    float o[4] = {0.f, 0.f, 0.f, 0.f};
#pragma unroll
    for (int s = 0; s < NS; ++s) {
        union { unsigned long long u64; unsigned short us[4]; } pk;
        pk.u64 = *reinterpret_cast<const unsigned long long*>(
            pO + (size_t)s * BB * GG * DD + base);
#pragma unroll
        for (int j = 0; j < 4; ++j) o[j] += b2f(pk.us[j]);
    }
    float4 v;
    v.x = o[0] * inv; v.y = o[1] * inv; v.z = o[2] * inv; v.w = o[3] * inv;
    *reinterpret_cast<float4*>(out + base) = v;
}

// ---------------- non-split flash (mid-ws fallback, proven R3/R4 path) ----------------
__global__ __launch_bounds__(256, 2)
void attn2ns(const ushort_t* __restrict__ emb,
             const ushort_t* __restrict__ embT,
             const ushort_t* __restrict__ qb,
             const int* __restrict__ real_len,
             float* __restrict__ outp) {
    __shared__ __align__(16) ushort_t sA[32 * 520];
    __shared__ __align__(16) ushort_t sP[32 * 40];
    __shared__ float s_lred[2][32];

    const int idx = blockIdx.x;
    const int xcd = idx & 7;
    const int gt = (idx >> 3) & 31;
    const int b = xcd + ((idx >> 8) << 3);
    const int g0 = gt * 32;

    const int tid = threadIdx.x;
    const int lane = tid & 63;
    const int w = tid >> 6;
    const int l15 = lane & 15;
    const int quad = lane >> 4;
    const int mt1 = w >> 1;
    const int gt1 = w & 1;

    short8 qf[16];
    {
        const ushort_t* qrow = qb + (size_t)(g0 + gt1 * 16 + l15) * DD + quad * 8;
#pragma unroll
        for (int kc = 0; kc < 16; ++kc)
            qf[kc] = *reinterpret_cast<const short8*>(qrow + kc * 32);
    }

    const ushort_t* embB  = emb  + (size_t)b * NN * DD;
    const ushort_t* embTB = embT + (size_t)b * DD * NN;

    const int rl0 = real_len[b];
    const int rl1 = real_len[BB + b];
    const int e0 = (rl0 + 31) >> 5;
    const int count = e0 + ((rl1 + 31) >> 5);

    f32x4 accO[8][2];
#pragma unroll
    for (int i = 0; i < 8; ++i) { accO[i][0] = (f32x4)0.f; accO[i][1] = (f32x4)0.f; }
    float ls = 0.f;

    auto stage = [&](int nt) {
        const ushort_t* src = embB + (size_t)(nt * 32 + w * 8) * DD + lane * 8;
        ushort_t* dst = sA + (w * 8) * 520;
#pragma unroll
        for (int i = 0; i < 8; ++i) {
            __builtin_amdgcn_global_load_lds(
                (const __attribute__((address_space(1))) unsigned int*)(src + (size_t)i * DD),
                (__attribute__((address_space(3))) unsigned int*)(dst + i * 520),
                16, 0, 0);
        }
    };
    short8 tf[8];
    auto prefetchT = [&](int nt) {
        const ushort_t* trow = embTB + (size_t)(w * 128 + l15) * NN + nt * 32 + quad * 8;
#pragma unroll
        for (int mt = 0; mt < 8; ++mt)
            tf[mt] = *reinterpret_cast<const short8*>(trow + (size_t)mt * 16 * NN);
    };

    int cur = 0;
    stage(0); prefetchT(0);

    for (int k = 0; k < count; ++k) {
        const int nxt = (cur + 1 == e0) ? 64 : cur + 1;
        __syncthreads();
        f32x4 S0 = (f32x4)0.f, S1 = (f32x4)0.f;
        {
            const ushort_t* arow = sA + (mt1 * 16 + l15) * 520 + quad * 8;
#pragma unroll
            for (int kc = 0; kc < 8; ++kc) {
                short8 a0 = *reinterpret_cast<const short8*>(arow + (2 * kc) * 32);
                short8 a1 = *reinterpret_cast<const short8*>(arow + (2 * kc + 1) * 32);
                S0 = __builtin_amdgcn_mfma_f32_16x16x32_bf16(a0, qf[2 * kc],     S0, 0, 0, 0);
                S1 = __builtin_amdgcn_mfma_f32_16x16x32_bf16(a1, qf[2 * kc + 1], S1, 0, 0, 0);
            }
        }
        const int n0 = cur * 32;
        const int nb = n0 + mt1 * 16 + quad * 4;
        const int rl = (nb >= LL) ? rl1 : rl0;
        const int lb = nb & (LL - 1);
        float p[4];
#pragma unroll
        for (int r = 0; r < 4; ++r)
            p[r] = (lb + r < rl) ? exp2f(S0[r] + S1[r] - 4.0f) : 0.0f;
        ls += (p[0] + p[1]) + (p[2] + p[3]);
        {
            union { unsigned short us[4]; unsigned long long u64; } pk;
            pk.us[0] = f2b(p[0]); pk.us[1] = f2b(p[1]); pk.us[2] = f2b(p[2]); pk.us[3] = f2b(p[3]);
            *reinterpret_cast<unsigned long long*>(
                sP + (gt1 * 16 + l15) * 40 + mt1 * 16 + quad * 4) = pk.u64;
        }
        __syncthreads();
        if (k + 1 < count) stage(nxt);
        {
            short8 bP0 = *reinterpret_cast<const short8*>(sP + l15 * 40 + quad * 8);
            short8 bP1 = *reinterpret_cast<const short8*>(sP + (16 + l15) * 40 + quad * 8);
#pragma unroll
            for (int mt = 0; mt < 8; ++mt) {
                accO[mt][0] = __builtin_amdgcn_mfma_f32_16x16x32_bf16(tf[mt], bP0, accO[mt][0], 0, 0, 0);
                accO[mt][1] = __builtin_amdgcn_mfma_f32_16x16x32_bf16(tf[mt], bP1, accO[mt][1], 0, 0, 0);
            }
        }
        if (k + 1 < count) prefetchT(nxt);
        cur = nxt;
    }

    ls += __shfl_xor(ls, 16, 64);
    ls += __shfl_xor(ls, 32, 64);
    if (lane < 16) s_lred[mt1][gt1 * 16 + lane] = ls;
    __syncthreads();

    const float il0 = 1.f / (s_lred[0][l15] + s_lred[1][l15]);
    const float il1 = 1.f / (s_lred[0][16 + l15] + s_lred[1][16 + l15]);
#pragma unroll
    for (int mt = 0; mt < 8; ++mt) {
#pragma unroll
        for (int gtt = 0; gtt < 2; ++gtt) {
            const float il = gtt ? il1 : il0;
            float4 v;
            v.x = accO[mt][gtt][0] * il; v.y = accO[mt][gtt][1] * il;
            v.z = accO[mt][gtt][2] * il; v.w = accO[mt][gtt][3] * il;
            const int g = g0 + gtt * 16 + l15;
            const int d = w * 128 + mt * 16 + quad * 4;
            *reinterpret_cast<float4*>(outp + ((size_t)b * GG + g) * DD + d) = v;
        }
    }
}

// ---------------- round-2 proven fallback (tiny ws) ----------------
__global__ void emb_kernel(const float* __restrict__ times,
                           const float* __restrict__ type_emb,
                           ushort_t* __restrict__ emb) {
    const int row = blockIdx.x;
    const int b = row >> 12;
    const int n = row & (NN - 1);
    const int t = n >> 11;
    const int l = n & (LL - 1);
    const float tm = times[(size_t)(t * BB + b) * LL + l];
    const float pad = (tm != 0.0f) ? 1.0f : 0.0f;
    const int tid = threadIdx.x;
#pragma unroll
    for (int i = 0; i < 2; ++i) {
        int d = i * 256 + tid;
        float theta = tm * inv_pos_f(d >> 1);
        float v = (d & 1) ? cosf(theta) : sinf(theta);
        v = (v + type_emb[t * DD + d]) * pad;
        emb[(size_t)row * DD + d] = f2b(v);
    }
}
__global__ void qgrid_kernel(float* __restrict__ qbuf) {
    const int g = blockIdx.x;
    const int tid = threadIdx.x;
    const float mid = (float)g + 0.5f;
#pragma unroll
    for (int i = 0; i < 4; ++i) {
        int d = i * 128 + tid;
        float theta = mid * inv_pos_f(d >> 1);
        float v = (d & 1) ? cosf(theta) : sinf(theta);
        qbuf[(size_t)g * DD + d] = v;
    }
}
__global__ void attn_kernel(const ushort_t* __restrict__ emb,
                            const float* __restrict__ qbuf,
                            const int* __restrict__ real_len,
                            float* __restrict__ out) {
    __shared__ float s_lds[NN];
    __shared__ float q_s[DD];
    __shared__ float red[8];
    const int blk = blockIdx.x;
    const int b = blk >> 10;
    const int g = blk & (GG - 1);
    const int tid = threadIdx.x;
    const int lane = tid & 63;
    const int wave = tid >> 6;
    q_s[tid]       = qbuf[(size_t)g * DD + tid];
    q_s[tid + 256] = qbuf[(size_t)g * DD + tid + 256];
    __syncthreads();
    float qr[8];
#pragma unroll
    for (int j = 0; j < 8; ++j) qr[j] = q_s[lane * 8 + j];
    const unsigned int* embB =
        reinterpret_cast<const unsigned int*>(emb) + (size_t)b * NN * (DD / 2);
#pragma unroll 2
    for (int it = 0; it < NN / 4; ++it) {
        const int n = it * 4 + wave;
        const uint4 raw = *reinterpret_cast<const uint4*>(embB + (size_t)n * (DD / 2) + lane * 4);
        float sacc = 0.f;
        sacc = fmaf(__uint_as_float(raw.x << 16),         qr[0], sacc);
        sacc = fmaf(__uint_as_float(raw.x & 0xffff0000u), qr[1], sacc);
        sacc = fmaf(__uint_as_float(raw.y << 16),         qr[2], sacc);
        sacc = fmaf(__uint_as_float(raw.y & 0xffff0000u), qr[3], sacc);
        sacc = fmaf(__uint_as_float(raw.z << 16),         qr[4], sacc);
        sacc = fmaf(__uint_as_float(raw.z & 0xffff0000u), qr[5], sacc);
        sacc = fmaf(__uint_as_float(raw.w << 16),         qr[6], sacc);
        sacc = fmaf(__uint_as_float(raw.w & 0xffff0000u), qr[7], sacc);
#pragma unroll
        for (int off = 32; off; off >>= 1) sacc += __shfl_xor(sacc, off, 64);
        if (lane == 0) s_lds[n] = sacc * SCALE;
    }
    __syncthreads();
    const int rl0 = real_len[b];
    const int rl1 = real_len[BB + b];
    float m = -INFINITY;
    float sv[16];
#pragma unroll
    for (int i = 0; i < 16; ++i) {
        const int n = i * 256 + tid;
        float sc = s_lds[n];
        const int l = n & (LL - 1);
        const bool valid = l < ((n < LL) ? rl0 : rl1);
        sc = valid ? sc : -INFINITY;
        sv[i] = sc;
        m = fmaxf(m, sc);
    }
#pragma unroll
    for (int off = 32; off; off >>= 1) m = fmaxf(m, __shfl_xor(m, off, 64));
    if (lane == 0) red[wave] = m;
    __syncthreads();
    m = fmaxf(fmaxf(red[0], red[1]), fmaxf(red[2], red[3]));
    float lsum = 0.f;
#pragma unroll
    for (int i = 0; i < 16; ++i) {
        const int n = i * 256 + tid;
        const float e = expf(sv[i] - m);
        s_lds[n] = e;
        lsum += e;
    }
#pragma unroll
    for (int off = 32; off; off >>= 1) lsum += __shfl_xor(lsum, off, 64);
    if (lane == 0) red[4 + wave] = lsum;
    __syncthreads();
    const float inv_l = 1.0f / (red[4] + red[5] + red[6] + red[7]);
    float acc[8] = {0.f, 0.f, 0.f, 0.f, 0.f, 0.f, 0.f, 0.f};
#pragma unroll 2
    for (int kk = 0; kk < NN / 4; ++kk) {
        const int n = kk * 4 + wave;
        const float p = s_lds[n];
        const uint4 raw = *reinterpret_cast<const uint4*>(embB + (size_t)n * (DD / 2) + lane * 4);
        acc[0] = fmaf(p, __uint_as_float(raw.x << 16),         acc[0]);
        acc[1] = fmaf(p, __uint_as_float(raw.x & 0xffff0000u), acc[1]);
        acc[2] = fmaf(p, __uint_as_float(raw.y << 16),         acc[2]);
        acc[3] = fmaf(p, __uint_as_float(raw.y & 0xffff0000u), acc[3]);
        acc[4] = fmaf(p, __uint_as_float(raw.z << 16),         acc[4]);
        acc[5] = fmaf(p, __uint_as_float(raw.z & 0xffff0000u), acc[5]);
        acc[6] = fmaf(p, __uint_as_float(raw.w << 16),         acc[6]);
        acc[7] = fmaf(p, __uint_as_float(raw.w & 0xffff0000u), acc[7]);
    }
    __syncthreads();
    *reinterpret_cast<float4*>(&s_lds[wave * DD + lane * 8])     = make_float4(acc[0], acc[1], acc[2], acc[3]);
    *reinterpret_cast<float4*>(&s_lds[wave * DD + lane * 8 + 4]) = make_float4(acc[4], acc[5], acc[6], acc[7]);
    __syncthreads();
    {
        const int d0 = tid * 2;
        const float o0 = (s_lds[d0]     + s_lds[DD + d0]     + s_lds[2 * DD + d0]     + s_lds[3 * DD + d0])     * inv_l;
        const float o1 = (s_lds[d0 + 1] + s_lds[DD + d0 + 1] + s_lds[2 * DD + d0 + 1] + s_lds[3 * DD + d0 + 1]) * inv_l;
        *reinterpret_cast<float2*>(out + (size_t)blk * DD + d0) = make_float2(o0, o1);
    }
}

extern "C" void kernel_launch(void* const* d_in, const int* in_sizes, int n_in,
                              void* d_out, int out_size, void* d_ws, size_t ws_size,
                              hipStream_t stream) {
    const float* times    = (const float*)d_in[0];
    const float* type_emb = (const float*)d_in[1];
    const int*   real_len = (const int*)d_in[2];
    float* out = (float*)d_out;

    const size_t embBytes = (size_t)BB * NN * DD * sizeof(ushort_t);     // 64 MiB
    const size_t qbBytes  = (size_t)GG * DD * sizeof(ushort_t);          // 1 MiB
    const size_t pOslice  = (size_t)BB * GG * DD * sizeof(ushort_t);     // 16 MiB (bf16)
    const size_t plslice  = (size_t)BB * GG * sizeof(float);             // 64 KiB
    const size_t needFast = 2 * embBytes + qbBytes;                      // 129 MiB
    const size_t need4 = needFast + 4 * (pOslice + plslice);             // ~193.3 MiB
    const size_t need2 = needFast + 2 * (pOslice + plslice);             // ~161.1 MiB

    ushort_t* emb = (ushort_t*)d_ws;

    if (ws_size >= needFast) {
        ushort_t* embT = (ushort_t*)((char*)d_ws + embBytes);
        ushort_t* qb   = (ushort_t*)((char*)d_ws + 2 * embBytes);
        gen_kernel<<<BB * 64, 256, 0, stream>>>(times, type_emb, emb, embT);
        qb_kernel<<<GG, 128, 0, stream>>>(qb);
        if (ws_size >= need4) {
            ushort_t* pO = (ushort_t*)((char*)d_ws + needFast);
            float* pl = (float*)((char*)d_ws + needFast + 4 * pOslice);
            attn3<4><<<4 * 512, 256, 0, stream>>>(emb, embT, qb, real_len, pO, pl);
            combine3<4><<<(BB * GG * DD) / (256 * 4), 256, 0, stream>>>(pO, pl, out);
        } else if (ws_size >= need2) {
            ushort_t* pO = (ushort_t*)((char*)d_ws + needFast);
            float* pl = (float*)((char*)d_ws + needFast + 2 * pOslice);
            attn3<2><<<2 * 512, 256, 0, stream>>>(emb, embT, qb, real_len, pO, pl);
            combine3<2><<<(BB * GG * DD) / (256 * 4), 256, 0, stream>>>(pO, pl, out);
        } else {
            attn2ns<<<512, 256, 0, stream>>>(emb, embT, qb, real_len, out);
        }
    } else {
        // fallback: 66 MiB footprint (proven in round 2)
        float* qbuf = (float*)((char*)d_ws + embBytes);
        emb_kernel<<<BB * NN, 256, 0, stream>>>(times, type_emb, emb);
        qgrid_kernel<<<GG, 128, 0, stream>>>(qbuf);
        attn_kernel<<<BB * GG, 256, 0, stream>>>(emb, qbuf, real_len, out);
    }
}